// Round 7
// baseline (257.307 us; speedup 1.0000x reference)
//
#include <hip/hip_runtime.h>

// SAM ViT-B global attention, MI355X bf16-MFMA implementation.
// R7: flash reads K/V fragments DIRECTLY from L2 (fragment-major layouts
//     k_f/v_f emitted by gemm<0>), no LDS staging, no main-loop barriers;
//     K pre-scaled by 0.125*log2e; rel_w bias as MFMA C-init; XCD swizzle
//     on gemms. lBH (rel_h) stays in LDS (16.6KB).

typedef __bf16 bf16;
typedef __bf16 bf16x8 __attribute__((ext_vector_type(8)));
typedef __bf16 bf16x4 __attribute__((ext_vector_type(4)));
typedef float f32x4 __attribute__((ext_vector_type(4)));
typedef float f32x16 __attribute__((ext_vector_type(16)));
typedef unsigned int u32;

__device__ __forceinline__ f32x4 mfma16(bf16x8 a, bf16x8 b, f32x4 c) {
  return __builtin_amdgcn_mfma_f32_16x16x32_bf16(a, b, c, 0, 0, 0);
}
__device__ __forceinline__ f32x16 mfma32(bf16x8 a, bf16x8 b, f32x16 c) {
  return __builtin_amdgcn_mfma_f32_32x32x16_bf16(a, b, c, 0, 0, 0);
}

typedef const __attribute__((address_space(1))) void* gas_ptr;
typedef __attribute__((address_space(3))) void* las_ptr;
__device__ __forceinline__ void gl_lds16(const void* g, void* l) {
  __builtin_amdgcn_global_load_lds((gas_ptr)g, (las_ptr)l, 16, 0, 0);
}

#if defined(__has_builtin)
#if __has_builtin(__builtin_amdgcn_permlane32_swap)
#define HAVE_PLSWAP 1
#endif
#endif
__device__ __forceinline__ void pswap_u(u32& a, u32& b) {
#ifdef HAVE_PLSWAP
  auto r = __builtin_amdgcn_permlane32_swap(a, b, false, false);
  a = r[0]; b = r[1];
#else
  const bool hi = (threadIdx.x & 32) != 0;
  u32 sa = (u32)__shfl_xor((int)a, 32, 64);
  u32 sb = (u32)__shfl_xor((int)b, 32, 64);
  u32 na = hi ? sb : a;
  u32 nb = hi ? b : sa;
  a = na; b = nb;
#endif
}
__device__ __forceinline__ void pswap_f(float& a, float& b) {
  u32 x = __float_as_uint(a), y = __float_as_uint(b);
  pswap_u(x, y);
  a = __uint_as_float(x); b = __uint_as_float(y);
}

#define L2E 1.4426950408889634f
#define SCK 0.18033688011112042f  // 0.125 * log2(e), folded into k_f

// ---------------- fp32 -> bf16 convert, 3 tensors in one launch ----------------
__global__ __launch_bounds__(256) void cvt3(
    const float* __restrict__ a, bf16* __restrict__ oa,
    const float* __restrict__ b, bf16* __restrict__ ob,
    const float* __restrict__ c, bf16* __restrict__ oc) {
  int blk = blockIdx.x;
  const float* src;
  bf16* dst;
  int base;
  if (blk < 1536)       { src = a; dst = oa; base = blk; }
  else if (blk < 2400)  { src = b; dst = ob; base = blk - 1536; }
  else                  { src = c; dst = oc; base = blk - 2400; }
  int idx = (base * 256 + threadIdx.x) * 8;
  f32x4 x = *(const f32x4*)&src[idx];
  f32x4 y = *(const f32x4*)&src[idx + 4];
  bf16x8 o;
#pragma unroll
  for (int j = 0; j < 4; j++) { o[j] = (bf16)x[j]; o[j + 4] = (bf16)y[j]; }
  *(bf16x8*)&dst[idx] = o;
}

// ---------------- 128x128 GEMM, BK=64, C = A @ B^T + bias ----------------
// MODE 0 epilogue: q -> q_s[head][m][hd] row-major;
//   k -> k_f fragment-major, PRE-SCALED by SCK:
//     idx = (((((head*64+t)*2+kh2)*4+s)*2+h)*32+r5)*8 + j
//     (t=m>>6, kh2=(m>>5)&1, r5=m&31, s=hd>>4, h=(hd>>3)&1, j=hd&7)
//   v -> v_f fragment-major via LDS-bounce transpose:
//     idx = (((((head*64+t)*2+kh2)*2+st)*2+hh)*64+hd)*8 + (m&7)
//     (st=(m>>4)&1, hh=(m>>3)&1)
// MODE 1: fp32 out [M][N].
template <int MODE>
__global__ __launch_bounds__(256) void gemm128(
    const bf16* __restrict__ A, const bf16* __restrict__ B,
    const float* __restrict__ bias, int K, int N,
    bf16* __restrict__ q_s, bf16* __restrict__ k_f, bf16* __restrict__ v_f,
    float* __restrict__ outf) {
  __shared__ __align__(16) bf16 lA[128 * 64];
  __shared__ __align__(16) bf16 lB[128 * 64];
  const int tid = threadIdx.x;
  const int w = tid >> 6, l = tid & 63;
  // XCD-aware flat-block swizzle (grid x*y divisible by 8)
  const int nbx = gridDim.x;
  const int flat = blockIdx.y * nbx + blockIdx.x;
  const int nwg = nbx * gridDim.y;
  const int idx = (flat & 7) * (nwg >> 3) + (flat >> 3);
  const int n0 = (idx % nbx) * 128, m0 = (idx / nbx) * 128;

  f32x4 acc[4][4] = {};

  int rowc[4], sloc[4];
#pragma unroll
  for (int j = 0; j < 4; j++) {
    const int c = w * 4 + j;
    rowc[j] = c * 8 + (l >> 3);
    sloc[j] = (((l & 7) ^ (l >> 3) ^ c) & 7) * 8;
  }
  const int mw = (w & 1) * 64, nw = (w >> 1) * 64;

  for (int k0 = 0; k0 < K; k0 += 64) {
    __syncthreads();
#pragma unroll
    for (int j = 0; j < 4; j++) {
      gl_lds16(&A[(size_t)(m0 + rowc[j]) * K + k0 + sloc[j]],
               (char*)lA + (w * 4 + j) * 1024);
      gl_lds16(&B[(size_t)(n0 + rowc[j]) * K + k0 + sloc[j]],
               (char*)lB + (w * 4 + j) * 1024);
    }
    __syncthreads();
    bf16x8 af[2][4], bfr[2][4];
#pragma unroll
    for (int ks = 0; ks < 2; ks++)
#pragma unroll
      for (int i = 0; i < 4; i++) {
        const int rA = mw + i * 16 + (l & 15);
        const int rB = nw + i * 16 + (l & 15);
        const int slot = ks * 4 + (l >> 4);
        const int fA = ((rA ^ (rA >> 3)) & 7), fB = ((rB ^ (rB >> 3)) & 7);
        af[ks][i] = *(const bf16x8*)((const char*)lA + rA * 128 + ((slot ^ fA) & 7) * 16);
        bfr[ks][i] = *(const bf16x8*)((const char*)lB + rB * 128 + ((slot ^ fB) & 7) * 16);
      }
#pragma unroll
    for (int ks = 0; ks < 2; ks++)
#pragma unroll
      for (int mi = 0; mi < 4; mi++)
#pragma unroll
        for (int ni = 0; ni < 4; ni++)
          acc[mi][ni] = mfma16(af[ks][mi], bfr[ks][ni], acc[mi][ni]);
  }

  if (MODE == 0 && n0 >= 1536) {
    // ---- V block: transpose via LDS bounce, b128 stores into v_f ----
    bf16* Lt = lA;
#pragma unroll 1
    for (int pass = 0; pass < 2; ++pass) {
      __syncthreads();
      if ((w >> 1) == pass) {
        char* R = (char*)Lt + (w & 1) * 8192;
#pragma unroll
        for (int ni = 0; ni < 4; ni++) {
          const float bv = bias[n0 + nw + ni * 16 + (l & 15)];
          const int nl = ni * 16 + (l & 15);
#pragma unroll
          for (int mi = 0; mi < 4; mi++)
#pragma unroll
            for (int i2 = 0; i2 < 2; i2++) {
              const int ml2 = (mi * 16 + (l >> 4) * 4 + i2 * 2) * 2;
              union { bf16 b[2]; u32 u; } pk;
              pk.b[0] = (bf16)(acc[mi][ni][i2 * 2] + bv);
              pk.b[1] = (bf16)(acc[mi][ni][i2 * 2 + 1] + bv);
              *(u32*)(R + nl * 128 + (ml2 ^ ((nl & 7) << 4))) = pk.u;
            }
        }
      }
      __syncthreads();
      if ((w >> 1) == pass) {
        const char* R = (const char*)Lt + (w & 1) * 8192;
#pragma unroll
        for (int r = 0; r < 8; r++) {
          const int nl = r * 8 + (l >> 3);   // hd index
          const int pc = ((l & 7) * 16) ^ ((nl & 7) << 4);
          bf16x8 val = *(const bf16x8*)(R + nl * 128 + pc);
          const int n = n0 + pass * 64 + nl;
          const int head = (n - 1536) >> 6, hd = n & 63;
          const int mg = m0 + (w & 1) * 64 + (l & 7) * 8;  // run of 8 tokens
          const int t = mg >> 6, kh2 = (mg >> 5) & 1;
          const int st = (mg >> 4) & 1, hh = (mg >> 3) & 1;
          const size_t vidx =
              ((((((size_t)head * 64 + t) * 2 + kh2) * 2 + st) * 2 + hh) * 64 +
               hd) * 8;
          *(bf16x8*)&v_f[vidx] = val;
        }
      }
    }
    return;
  }

#pragma unroll
  for (int ni = 0; ni < 4; ni++) {
    const int n = n0 + nw + ni * 16 + (l & 15);
    const float bv = bias[n];
#pragma unroll
    for (int mi = 0; mi < 4; mi++) {
#pragma unroll
      for (int i = 0; i < 4; i++) {
        const int m = m0 + mw + mi * 16 + (l >> 4) * 4 + i;
        const float v = acc[mi][ni][i] + bv;
        if (MODE == 0) {
          const int which = n / 768, hn = n % 768;
          const int head = hn >> 6, hd = hn & 63;
          if (which == 0) {
            q_s[((size_t)head * 4096 + m) * 64 + hd] = (bf16)v;
          } else {
            const int t = m >> 6, kh2 = (m >> 5) & 1, r5 = m & 31;
            const int s = hd >> 4, h = (hd >> 3) & 1, j = hd & 7;
            const size_t kidx =
                ((((((size_t)head * 64 + t) * 2 + kh2) * 4 + s) * 2 + h) * 32 +
                 r5) * 8 + j;
            k_f[kidx] = (bf16)(v * SCK);
          }
        } else {
          outf[(size_t)m * N + n] = v;
        }
      }
    }
  }
}

// ---------------- rel_w bias kernel ----------------
__global__ __launch_bounds__(64) void rel_pos_w(
    const bf16* __restrict__ q_s, const float* __restrict__ table,
    float* __restrict__ out) {
  const int l = threadIdx.x;
  const int p = blockIdx.x, head = blockIdx.y;
  const size_t hbase = (size_t)head * 4096 * 64;

  f32x4 acc[4][4] = {};
#pragma unroll
  for (int ks = 0; ks < 2; ks++) {
    bf16x8 af[4], bfr[4];
#pragma unroll
    for (int mi = 0; mi < 4; mi++) {
      const int row = mi * 16 + (l & 15);
      const int s = row * 64 + p;
      af[mi] = *(const bf16x8*)&q_s[hbase + (size_t)s * 64 + ks * 32 + (l >> 4) * 8];
    }
#pragma unroll
    for (int ni = 0; ni < 4; ni++) {
      const int col = ni * 16 + (l & 15);
      const float* tp = &table[(size_t)(p - col + 63) * 64 + ks * 32 + (l >> 4) * 8];
      f32x4 t0 = *(const f32x4*)tp;
      f32x4 t1 = *(const f32x4*)(tp + 4);
      bf16x8 bb;
#pragma unroll
      for (int j = 0; j < 4; j++) { bb[j] = (bf16)t0[j]; bb[j + 4] = (bf16)t1[j]; }
      bfr[ni] = bb;
    }
#pragma unroll
    for (int mi = 0; mi < 4; mi++)
#pragma unroll
      for (int ni = 0; ni < 4; ni++)
        acc[mi][ni] = mfma16(af[mi], bfr[ni], acc[mi][ni]);
  }
#pragma unroll
  for (int mi = 0; mi < 4; mi++)
#pragma unroll
    for (int ni = 0; ni < 4; ni++)
#pragma unroll
      for (int i = 0; i < 4; i++) {
        const int row = mi * 16 + (l >> 4) * 4 + i;
        const int col = ni * 16 + (l & 15);
        const int sq = row * 64 + p;
        out[hbase + (size_t)sq * 64 + col] = acc[mi][ni][i];
      }
}

// ---------------- flash attention: L2-direct fragments, barrier-free loop ----
// Grid: 768 linear blocks, XCD-pinned decode. Wave w: qg=w&1 (32 queries),
// kh2=w>>1 (32 of 64 keys per tile). K pre-scaled by SCK, c2 as MFMA C-init:
// p[j] = sacc[j] in log2 domain directly.
__global__ __launch_bounds__(256, 3) void flash_attn(
    const bf16* __restrict__ q_s, const bf16* __restrict__ k_f,
    const bf16* __restrict__ v_f, const float* __restrict__ rph,
    const float* __restrict__ bias_w, bf16* __restrict__ attn_out) {
  __shared__ __align__(16) char smem[16896];
  float* lBH = (float*)smem;  // [64][65] rel_h bias * L2E (merge area overlaps after loop)

  const int tid = threadIdx.x;
  const int w = tid >> 6, l = tid & 63;
  const int r5 = l & 31, h = l >> 5;
  const int qg = w & 1, kh2 = w >> 1;
  const int f = blockIdx.x;
  const int g = (f & 7) * 96 + (f >> 3);
  const int head = g >> 6, qh = g & 63;
  const size_t hbase = (size_t)head << 18;  // 4096*64 per head (q_s/bias_w/k_f/v_f)
  const int qloc = qg * 32 + r5;
  const size_t sq = (size_t)qh * 64 + qloc;

  // ---- prologue: fused rel_h -> lBH[q][kh] * L2E (16x16 MFMA) ----
  {
    const int q16 = l & 15, g4 = l >> 4;
    const size_t sq16 = (size_t)qh * 64 + w * 16 + q16;
    bf16x8 qf16[2];
    qf16[0] = *(const bf16x8*)&q_s[hbase + sq16 * 64 + g4 * 8];
    qf16[1] = *(const bf16x8*)&q_s[hbase + sq16 * 64 + 32 + g4 * 8];
    f32x4 abh[4] = {};
#pragma unroll
    for (int ks = 0; ks < 2; ks++)
#pragma unroll
      for (int ni = 0; ni < 4; ni++) {
        const int kh = ni * 16 + q16;
        const float* tp = &rph[(size_t)(qh + 63 - kh) * 64 + ks * 32 + g4 * 8];
        f32x4 t0 = *(const f32x4*)tp;
        f32x4 t1 = *(const f32x4*)(tp + 4);
        bf16x8 rf;
#pragma unroll
        for (int j = 0; j < 4; j++) { rf[j] = (bf16)t0[j]; rf[j + 4] = (bf16)t1[j]; }
        abh[ni] = mfma16(rf, qf16[ks], abh[ni]);
      }
#pragma unroll
    for (int ni = 0; ni < 4; ni++)
#pragma unroll
      for (int i = 0; i < 4; i++)
        lBH[(w * 16 + q16) * 65 + ni * 16 + g4 * 4 + i] = abh[ni][i] * L2E;
  }

  // ---- Q fragments (32x32 B-operand) ----
  bf16x8 qv[4];
#pragma unroll
  for (int s = 0; s < 4; s++)
    qv[s] = *(const bf16x8*)&q_s[hbase + sq * 64 + s * 16 + h * 8];

  // rel_w bias (exp2 domain) in MFMA C-reg order, as the C-init vector
  f32x16 c2v;
#pragma unroll
  for (int G = 0; G < 4; G++) {
    f32x4 cv = *(const f32x4*)&bias_w[hbase + sq * 64 + kh2 * 32 + G * 8 + h * 4];
#pragma unroll
    for (int i = 0; i < 4; i++) c2v[G * 4 + i] = cv[i] * L2E;
  }

  // fragment-major pointers (advance 4096 elems = 8KB per tile)
  const bf16* kp = k_f + hbase + kh2 * 2048 + h * 256 + r5 * 8;
  const bf16* vp = v_f + hbase + kh2 * 2048 + h * 512 + r5 * 8;
  const float* lbhp = lBH + qloc * 65;

  f32x16 o[2] = {};
  float mrun = -1e30f, lrun = 0.f;

  __syncthreads();  // lBH ready

  for (int t = 0; t < 64; t++) {
    // ---- QK^T: 4 K-steps, operands straight from L2 ----
    f32x16 sacc = c2v;
    __builtin_amdgcn_s_setprio(1);
#pragma unroll
    for (int s = 0; s < 4; s++) {
      bf16x8 kf = *(const bf16x8*)((const char*)kp + s * 1024);
      sacc = mfma32(kf, qv[s], sacc);
    }
    __builtin_amdgcn_s_setprio(0);

    // ---- softmax (log2 domain; lane pair l, l+32 shares query) ----
    float pm = fmaxf(
        fmaxf(fmaxf(fmaxf(sacc[0], sacc[1]), sacc[2]),
              fmaxf(fmaxf(sacc[3], sacc[4]), sacc[5])),
        fmaxf(fmaxf(fmaxf(sacc[6], sacc[7]), fmaxf(sacc[8], sacc[9])),
              fmaxf(fmaxf(sacc[10], fmaxf(sacc[11], sacc[12])),
                    fmaxf(sacc[13], fmaxf(sacc[14], sacc[15])))));
    { float t2 = pm; pswap_f(t2, pm); pm = fmaxf(t2, pm); }
    const float bh2 = lbhp[t];
    const float rmf = pm + bh2;

    if (!__all(rmf - mrun <= 8.f)) {
      const float mn = fmaxf(mrun, rmf);
      const float al = __builtin_amdgcn_exp2f(mrun - mn);
      mrun = mn;
      lrun *= al;
      o[0] *= al;
      o[1] *= al;
    }

    const float d = bh2 - mrun;
    float rs = 0.f;
    u32 w8[8];
#pragma unroll
    for (int j = 0; j < 8; j++) {
      float e0 = __builtin_amdgcn_exp2f(sacc[2 * j] + d);
      float e1 = __builtin_amdgcn_exp2f(sacc[2 * j + 1] + d);
      rs += e0 + e1;
      union { bf16 b[2]; u32 u; } cvu;
      cvu.b[0] = (bf16)e0;
      cvu.b[1] = (bf16)e1;
      w8[j] = cvu.u;
    }
    { float t2 = rs; pswap_f(t2, rs); rs = t2 + rs; }
    lrun += rs;

    // ---- PV: B-fragments via permlane swaps, V straight from L2 ----
#pragma unroll
    for (int st = 0; st < 2; st++) {
      union { u32 u[4]; bf16x8 v; } pf;
      u32 a0 = w8[4 * st], b0 = w8[4 * st + 2];
      u32 a1 = w8[4 * st + 1], b1 = w8[4 * st + 3];
      pswap_u(a0, b0);
      pswap_u(a1, b1);
      pf.u[0] = a0; pf.u[1] = a1; pf.u[2] = b0; pf.u[3] = b1;
      __builtin_amdgcn_s_setprio(1);
#pragma unroll
      for (int T = 0; T < 2; T++) {
        bf16x8 vf = *(const bf16x8*)((const char*)vp + st * 2048 + T * 512);
        o[T] = mfma32(vf, pf.v, o[T]);
      }
      __builtin_amdgcn_s_setprio(0);
    }

    kp += 4096;
    vp += 4096;
  }

  __syncthreads();  // all compute done before LDS reuse

  // ---- merge key halves: waves 2,3 publish; waves 0,1 combine + store ----
  float* MM = (float*)smem;          // m [2][32]
  float* ML = (float*)(smem + 256);  // l [2][32]
  float* MO = (float*)(smem + 512);  // O [2][32][64]
  if (w >= 2) {
    if (h == 0) { MM[qg * 32 + r5] = mrun; ML[qg * 32 + r5] = lrun; }
#pragma unroll
    for (int T = 0; T < 2; T++)
#pragma unroll
      for (int G = 0; G < 4; G++) {
        f32x4 ov;
#pragma unroll
        for (int i = 0; i < 4; i++) ov[i] = o[T][4 * G + i];
        *(f32x4*)&MO[qg * 2048 + r5 * 64 + T * 32 + G * 8 + h * 4] = ov;
      }
  }
  __syncthreads();
  if (w < 2) {
    const float mp = MM[qg * 32 + r5], lp = ML[qg * 32 + r5];
    const float mT = fmaxf(mrun, mp);
    const float a = __builtin_amdgcn_exp2f(mrun - mT);
    const float b = __builtin_amdgcn_exp2f(mp - mT);
    const float inv = 1.f / (lrun * a + lp * b);
#pragma unroll
    for (int T = 0; T < 2; T++)
#pragma unroll
      for (int G = 0; G < 4; G++) {
        f32x4 po = *(const f32x4*)&MO[qg * 2048 + r5 * 64 + T * 32 + G * 8 + h * 4];
        bf16x4 ob;
#pragma unroll
        for (int i = 0; i < 4; i++)
          ob[i] = (bf16)((o[T][4 * G + i] * a + po[i] * b) * inv);
        *(bf16x4*)&attn_out[sq * 768 + head * 64 + T * 32 + G * 8 + h * 4] = ob;
      }
  }
}

// ---------------- launch ----------------
extern "C" void kernel_launch(void* const* d_in, const int* in_sizes, int n_in,
                              void* d_out, int out_size, void* d_ws, size_t ws_size,
                              hipStream_t stream) {
  const float* x      = (const float*)d_in[0];
  const float* qkv_w  = (const float*)d_in[1];
  const float* qkv_b  = (const float*)d_in[2];
  const float* proj_w = (const float*)d_in[3];
  const float* proj_b = (const float*)d_in[4];
  const float* rph    = (const float*)d_in[5];
  const float* rpw    = (const float*)d_in[6];

  char* ws = (char*)d_ws;
  bf16*  xb    = (bf16*)(ws);                 //  6.29 MB [4096][768]
  bf16*  wqkv  = (bf16*)(ws + 6291456);       //  3.54 MB [2304][768]
  bf16*  wproj = (bf16*)(ws + 9830400);       //  1.18 MB [768][768]
  bf16*  q_s   = (bf16*)(ws + 11010048);      //  6.29 MB [12][4096][64]
  bf16*  k_f   = (bf16*)(ws + 17301504);      //  6.29 MB fragment-major K (scaled)
  bf16*  v_f   = (bf16*)(ws + 23592960);      //  6.29 MB fragment-major V
  bf16*  attno = (bf16*)(ws + 29884416);      //  6.29 MB [4096][768]
  float* bwv   = (float*)(ws + 36175872);     // 12.58 MB [12][4096][64]

  cvt3<<<2688, 256, 0, stream>>>(x, xb, qkv_w, wqkv, proj_w, wproj);

  gemm128<0><<<dim3(18, 32), 256, 0, stream>>>(xb, wqkv, qkv_b, 768, 2304,
                                               q_s, k_f, v_f, nullptr);

  rel_pos_w<<<dim3(64, 12), 64, 0, stream>>>(q_s, rpw, bwv);

  flash_attn<<<768, 256, 0, stream>>>(q_s, k_f, v_f, rph, bwv, attno);

  gemm128<1><<<dim3(6, 32), 256, 0, stream>>>(attno, wproj, proj_b, 768, 768,
                                              nullptr, nullptr, nullptr,
                                              (float*)d_out);
}

// Round 8
// 247.762 us; speedup vs baseline: 1.0385x; 1.0385x over previous
//
#include <hip/hip_runtime.h>

// SAM ViT-B global attention, MI355X bf16-MFMA implementation.
// R8: flash = R7 (L2-direct fragments, barrier-free) + K register
//     double-buffer prefetch + V-at-top issue ordering (latency hiding);
//     rel-pos tables pre-converted to bf16 in cvt3.

typedef __bf16 bf16;
typedef __bf16 bf16x8 __attribute__((ext_vector_type(8)));
typedef __bf16 bf16x4 __attribute__((ext_vector_type(4)));
typedef float f32x4 __attribute__((ext_vector_type(4)));
typedef float f32x16 __attribute__((ext_vector_type(16)));
typedef unsigned int u32;

__device__ __forceinline__ f32x4 mfma16(bf16x8 a, bf16x8 b, f32x4 c) {
  return __builtin_amdgcn_mfma_f32_16x16x32_bf16(a, b, c, 0, 0, 0);
}
__device__ __forceinline__ f32x16 mfma32(bf16x8 a, bf16x8 b, f32x16 c) {
  return __builtin_amdgcn_mfma_f32_32x32x16_bf16(a, b, c, 0, 0, 0);
}

typedef const __attribute__((address_space(1))) void* gas_ptr;
typedef __attribute__((address_space(3))) void* las_ptr;
__device__ __forceinline__ void gl_lds16(const void* g, void* l) {
  __builtin_amdgcn_global_load_lds((gas_ptr)g, (las_ptr)l, 16, 0, 0);
}

#if defined(__has_builtin)
#if __has_builtin(__builtin_amdgcn_permlane32_swap)
#define HAVE_PLSWAP 1
#endif
#endif
__device__ __forceinline__ void pswap_u(u32& a, u32& b) {
#ifdef HAVE_PLSWAP
  auto r = __builtin_amdgcn_permlane32_swap(a, b, false, false);
  a = r[0]; b = r[1];
#else
  const bool hi = (threadIdx.x & 32) != 0;
  u32 sa = (u32)__shfl_xor((int)a, 32, 64);
  u32 sb = (u32)__shfl_xor((int)b, 32, 64);
  u32 na = hi ? sb : a;
  u32 nb = hi ? b : sa;
  a = na; b = nb;
#endif
}
__device__ __forceinline__ void pswap_f(float& a, float& b) {
  u32 x = __float_as_uint(a), y = __float_as_uint(b);
  pswap_u(x, y);
  a = __uint_as_float(x); b = __uint_as_float(y);
}

#define L2E 1.4426950408889634f
#define SCK 0.18033688011112042f  // 0.125 * log2(e), folded into k_f

// ------------- fp32 -> bf16 convert: 3 big tensors + 2 rel-pos tables -------
__global__ __launch_bounds__(256) void cvt3(
    const float* __restrict__ a, bf16* __restrict__ oa,
    const float* __restrict__ b, bf16* __restrict__ ob,
    const float* __restrict__ c, bf16* __restrict__ oc,
    const float* __restrict__ t1, bf16* __restrict__ ot1,
    const float* __restrict__ t2, bf16* __restrict__ ot2) {
  int blk = blockIdx.x;
  const float* src;
  bf16* dst;
  int base, lim;
  if (blk < 1536)       { src = a;  dst = oa;  base = blk;        lim = 3145728; }
  else if (blk < 2400)  { src = b;  dst = ob;  base = blk - 1536; lim = 1769472; }
  else if (blk < 2688)  { src = c;  dst = oc;  base = blk - 2400; lim = 589824; }
  else if (blk < 2692)  { src = t1; dst = ot1; base = blk - 2688; lim = 8128; }
  else                  { src = t2; dst = ot2; base = blk - 2692; lim = 8128; }
  int idx = (base * 256 + threadIdx.x) * 8;
  if (idx >= lim) return;
  f32x4 x = *(const f32x4*)&src[idx];
  f32x4 y = *(const f32x4*)&src[idx + 4];
  bf16x8 o;
#pragma unroll
  for (int j = 0; j < 4; j++) { o[j] = (bf16)x[j]; o[j + 4] = (bf16)y[j]; }
  *(bf16x8*)&dst[idx] = o;
}

// ---------------- 128x128 GEMM, BK=64, C = A @ B^T + bias ----------------
// MODE 0 epilogue: q -> q_s[head][m][hd] row-major;
//   k -> k_f fragment-major, PRE-SCALED by SCK;
//   v -> v_f fragment-major via LDS-bounce transpose.
// MODE 1: fp32 out [M][N].
template <int MODE>
__global__ __launch_bounds__(256) void gemm128(
    const bf16* __restrict__ A, const bf16* __restrict__ B,
    const float* __restrict__ bias, int K, int N,
    bf16* __restrict__ q_s, bf16* __restrict__ k_f, bf16* __restrict__ v_f,
    float* __restrict__ outf) {
  __shared__ __align__(16) bf16 lA[128 * 64];
  __shared__ __align__(16) bf16 lB[128 * 64];
  const int tid = threadIdx.x;
  const int w = tid >> 6, l = tid & 63;
  const int nbx = gridDim.x;
  const int flat = blockIdx.y * nbx + blockIdx.x;
  const int nwg = nbx * gridDim.y;
  const int idx = (flat & 7) * (nwg >> 3) + (flat >> 3);
  const int n0 = (idx % nbx) * 128, m0 = (idx / nbx) * 128;

  f32x4 acc[4][4] = {};

  int rowc[4], sloc[4];
#pragma unroll
  for (int j = 0; j < 4; j++) {
    const int c = w * 4 + j;
    rowc[j] = c * 8 + (l >> 3);
    sloc[j] = (((l & 7) ^ (l >> 3) ^ c) & 7) * 8;
  }
  const int mw = (w & 1) * 64, nw = (w >> 1) * 64;

  for (int k0 = 0; k0 < K; k0 += 64) {
    __syncthreads();
#pragma unroll
    for (int j = 0; j < 4; j++) {
      gl_lds16(&A[(size_t)(m0 + rowc[j]) * K + k0 + sloc[j]],
               (char*)lA + (w * 4 + j) * 1024);
      gl_lds16(&B[(size_t)(n0 + rowc[j]) * K + k0 + sloc[j]],
               (char*)lB + (w * 4 + j) * 1024);
    }
    __syncthreads();
    bf16x8 af[2][4], bfr[2][4];
#pragma unroll
    for (int ks = 0; ks < 2; ks++)
#pragma unroll
      for (int i = 0; i < 4; i++) {
        const int rA = mw + i * 16 + (l & 15);
        const int rB = nw + i * 16 + (l & 15);
        const int slot = ks * 4 + (l >> 4);
        const int fA = ((rA ^ (rA >> 3)) & 7), fB = ((rB ^ (rB >> 3)) & 7);
        af[ks][i] = *(const bf16x8*)((const char*)lA + rA * 128 + ((slot ^ fA) & 7) * 16);
        bfr[ks][i] = *(const bf16x8*)((const char*)lB + rB * 128 + ((slot ^ fB) & 7) * 16);
      }
#pragma unroll
    for (int ks = 0; ks < 2; ks++)
#pragma unroll
      for (int mi = 0; mi < 4; mi++)
#pragma unroll
        for (int ni = 0; ni < 4; ni++)
          acc[mi][ni] = mfma16(af[ks][mi], bfr[ks][ni], acc[mi][ni]);
  }

  if (MODE == 0 && n0 >= 1536) {
    bf16* Lt = lA;
#pragma unroll 1
    for (int pass = 0; pass < 2; ++pass) {
      __syncthreads();
      if ((w >> 1) == pass) {
        char* R = (char*)Lt + (w & 1) * 8192;
#pragma unroll
        for (int ni = 0; ni < 4; ni++) {
          const float bv = bias[n0 + nw + ni * 16 + (l & 15)];
          const int nl = ni * 16 + (l & 15);
#pragma unroll
          for (int mi = 0; mi < 4; mi++)
#pragma unroll
            for (int i2 = 0; i2 < 2; i2++) {
              const int ml2 = (mi * 16 + (l >> 4) * 4 + i2 * 2) * 2;
              union { bf16 b[2]; u32 u; } pk;
              pk.b[0] = (bf16)(acc[mi][ni][i2 * 2] + bv);
              pk.b[1] = (bf16)(acc[mi][ni][i2 * 2 + 1] + bv);
              *(u32*)(R + nl * 128 + (ml2 ^ ((nl & 7) << 4))) = pk.u;
            }
        }
      }
      __syncthreads();
      if ((w >> 1) == pass) {
        const char* R = (const char*)Lt + (w & 1) * 8192;
#pragma unroll
        for (int r = 0; r < 8; r++) {
          const int nl = r * 8 + (l >> 3);   // hd index
          const int pc = ((l & 7) * 16) ^ ((nl & 7) << 4);
          bf16x8 val = *(const bf16x8*)(R + nl * 128 + pc);
          const int n = n0 + pass * 64 + nl;
          const int head = (n - 1536) >> 6, hd = n & 63;
          const int mg = m0 + (w & 1) * 64 + (l & 7) * 8;
          const int t = mg >> 6, kh2 = (mg >> 5) & 1;
          const int st = (mg >> 4) & 1, hh = (mg >> 3) & 1;
          const size_t vidx =
              ((((((size_t)head * 64 + t) * 2 + kh2) * 2 + st) * 2 + hh) * 64 +
               hd) * 8;
          *(bf16x8*)&v_f[vidx] = val;
        }
      }
    }
    return;
  }

#pragma unroll
  for (int ni = 0; ni < 4; ni++) {
    const int n = n0 + nw + ni * 16 + (l & 15);
    const float bv = bias[n];
#pragma unroll
    for (int mi = 0; mi < 4; mi++) {
#pragma unroll
      for (int i = 0; i < 4; i++) {
        const int m = m0 + mw + mi * 16 + (l >> 4) * 4 + i;
        const float v = acc[mi][ni][i] + bv;
        if (MODE == 0) {
          const int which = n / 768, hn = n % 768;
          const int head = hn >> 6, hd = hn & 63;
          if (which == 0) {
            q_s[((size_t)head * 4096 + m) * 64 + hd] = (bf16)v;
          } else {
            const int t = m >> 6, kh2 = (m >> 5) & 1, r5 = m & 31;
            const int s = hd >> 4, h = (hd >> 3) & 1, j = hd & 7;
            const size_t kidx =
                ((((((size_t)head * 64 + t) * 2 + kh2) * 4 + s) * 2 + h) * 32 +
                 r5) * 8 + j;
            k_f[kidx] = (bf16)(v * SCK);
          }
        } else {
          outf[(size_t)m * N + n] = v;
        }
      }
    }
  }
}

// ---------------- rel_w bias kernel (bf16 table) ----------------
__global__ __launch_bounds__(64) void rel_pos_w(
    const bf16* __restrict__ q_s, const bf16* __restrict__ rpw_b,
    float* __restrict__ out) {
  const int l = threadIdx.x;
  const int p = blockIdx.x, head = blockIdx.y;
  const size_t hbase = (size_t)head * 4096 * 64;

  f32x4 acc[4][4] = {};
#pragma unroll
  for (int ks = 0; ks < 2; ks++) {
    bf16x8 af[4], bfr[4];
#pragma unroll
    for (int mi = 0; mi < 4; mi++) {
      const int row = mi * 16 + (l & 15);
      const int s = row * 64 + p;
      af[mi] = *(const bf16x8*)&q_s[hbase + (size_t)s * 64 + ks * 32 + (l >> 4) * 8];
    }
#pragma unroll
    for (int ni = 0; ni < 4; ni++) {
      const int col = ni * 16 + (l & 15);
      bfr[ni] = *(const bf16x8*)&rpw_b[(size_t)(p - col + 63) * 64 + ks * 32 +
                                       (l >> 4) * 8];
    }
#pragma unroll
    for (int mi = 0; mi < 4; mi++)
#pragma unroll
      for (int ni = 0; ni < 4; ni++)
        acc[mi][ni] = mfma16(af[mi], bfr[ni], acc[mi][ni]);
  }
#pragma unroll
  for (int mi = 0; mi < 4; mi++)
#pragma unroll
    for (int ni = 0; ni < 4; ni++)
#pragma unroll
      for (int i = 0; i < 4; i++) {
        const int row = mi * 16 + (l >> 4) * 4 + i;
        const int col = ni * 16 + (l & 15);
        const int sq = row * 64 + p;
        out[hbase + (size_t)sq * 64 + col] = acc[mi][ni][i];
      }
}

// ---------------- flash attention: L2-direct + register prefetch ----------
// Grid: 768 linear blocks, XCD-pinned. Wave w: qg=w&1 (32 queries),
// kh2=w>>1 (32 of 64 keys/tile). K double-buffered in regs (1 tile ahead);
// V issued at iter top BEFORE K-prefetch so PV's wait leaves K in flight.
__global__ __launch_bounds__(256, 3) void flash_attn(
    const bf16* __restrict__ q_s, const bf16* __restrict__ k_f,
    const bf16* __restrict__ v_f, const bf16* __restrict__ rph_b,
    const float* __restrict__ bias_w, bf16* __restrict__ attn_out) {
  __shared__ __align__(16) char smem[16896];
  float* lBH = (float*)smem;  // [64][65] rel_h bias * L2E

  const int tid = threadIdx.x;
  const int w = tid >> 6, l = tid & 63;
  const int r5 = l & 31, h = l >> 5;
  const int qg = w & 1, kh2 = w >> 1;
  const int f = blockIdx.x;
  const int g = (f & 7) * 96 + (f >> 3);
  const int head = g >> 6, qh = g & 63;
  const size_t hbase = (size_t)head << 18;
  const int qloc = qg * 32 + r5;
  const size_t sq = (size_t)qh * 64 + qloc;

  // ---- prologue: fused rel_h -> lBH[q][kh] * L2E (16x16 MFMA, bf16 table) ----
  {
    const int q16 = l & 15, g4 = l >> 4;
    const size_t sq16 = (size_t)qh * 64 + w * 16 + q16;
    bf16x8 qf16[2];
    qf16[0] = *(const bf16x8*)&q_s[hbase + sq16 * 64 + g4 * 8];
    qf16[1] = *(const bf16x8*)&q_s[hbase + sq16 * 64 + 32 + g4 * 8];
    f32x4 abh[4] = {};
#pragma unroll
    for (int ks = 0; ks < 2; ks++)
#pragma unroll
      for (int ni = 0; ni < 4; ni++) {
        const int kh = ni * 16 + q16;
        bf16x8 rf = *(const bf16x8*)&rph_b[(size_t)(qh + 63 - kh) * 64 +
                                           ks * 32 + g4 * 8];
        abh[ni] = mfma16(rf, qf16[ks], abh[ni]);
      }
#pragma unroll
    for (int ni = 0; ni < 4; ni++)
#pragma unroll
      for (int i = 0; i < 4; i++)
        lBH[(w * 16 + q16) * 65 + ni * 16 + g4 * 4 + i] = abh[ni][i] * L2E;
  }

  // ---- Q fragments (32x32 B-operand) ----
  bf16x8 qv[4];
#pragma unroll
  for (int s = 0; s < 4; s++)
    qv[s] = *(const bf16x8*)&q_s[hbase + sq * 64 + s * 16 + h * 8];

  // rel_w bias (exp2 domain) in MFMA C-reg order, as the C-init vector
  f32x16 c2v;
#pragma unroll
  for (int G = 0; G < 4; G++) {
    f32x4 cv = *(const f32x4*)&bias_w[hbase + sq * 64 + kh2 * 32 + G * 8 + h * 4];
#pragma unroll
    for (int i = 0; i < 4; i++) c2v[G * 4 + i] = cv[i] * L2E;
  }

  // fragment-major pointers (advance 4096 elems = 8KB per tile)
  const bf16* kp = k_f + hbase + kh2 * 2048 + h * 256 + r5 * 8;
  const bf16* vp = v_f + hbase + kh2 * 2048 + h * 512 + r5 * 8;
  const float* lbhp = lBH + qloc * 65;

  f32x16 o[2] = {};
  float mrun = -1e30f, lrun = 0.f;

  // K tile 0 preload (register double-buffer A)
  bf16x8 kA0 = *(const bf16x8*)(kp);
  bf16x8 kA1 = *(const bf16x8*)(kp + 512);
  bf16x8 kA2 = *(const bf16x8*)(kp + 1024);
  bf16x8 kA3 = *(const bf16x8*)(kp + 1536);
  kp += 4096;
  bf16x8 kB0, kB1, kB2, kB3, v0, v1, v2, v3;

#define COMP(K0, K1, K2, K3, t)                                              \
  do {                                                                       \
    f32x16 sacc = c2v;                                                       \
    __builtin_amdgcn_s_setprio(1);                                           \
    sacc = mfma32(K0, qv[0], sacc);                                          \
    sacc = mfma32(K1, qv[1], sacc);                                          \
    sacc = mfma32(K2, qv[2], sacc);                                          \
    sacc = mfma32(K3, qv[3], sacc);                                          \
    __builtin_amdgcn_s_setprio(0);                                           \
    float pm = fmaxf(                                                        \
        fmaxf(fmaxf(fmaxf(sacc[0], sacc[1]), sacc[2]),                       \
              fmaxf(fmaxf(sacc[3], sacc[4]), sacc[5])),                      \
        fmaxf(fmaxf(fmaxf(sacc[6], sacc[7]), fmaxf(sacc[8], sacc[9])),       \
              fmaxf(fmaxf(sacc[10], fmaxf(sacc[11], sacc[12])),              \
                    fmaxf(sacc[13], fmaxf(sacc[14], sacc[15])))));           \
    { float t2_ = pm; pswap_f(t2_, pm); pm = fmaxf(t2_, pm); }               \
    const float bh2 = lbhp[(t)];                                             \
    const float rmf = pm + bh2;                                              \
    if (!__all(rmf - mrun <= 8.f)) {                                         \
      const float mn = fmaxf(mrun, rmf);                                     \
      const float al = __builtin_amdgcn_exp2f(mrun - mn);                    \
      mrun = mn;                                                             \
      lrun *= al;                                                            \
      o[0] *= al;                                                            \
      o[1] *= al;                                                            \
    }                                                                        \
    const float d = bh2 - mrun;                                              \
    float rs = 0.f;                                                          \
    u32 w8[8];                                                               \
    _Pragma("unroll")                                                        \
    for (int j = 0; j < 8; j++) {                                            \
      float e0 = __builtin_amdgcn_exp2f(sacc[2 * j] + d);                    \
      float e1 = __builtin_amdgcn_exp2f(sacc[2 * j + 1] + d);                \
      rs += e0 + e1;                                                         \
      union { bf16 b[2]; u32 u; } cvu;                                       \
      cvu.b[0] = (bf16)e0;                                                   \
      cvu.b[1] = (bf16)e1;                                                   \
      w8[j] = cvu.u;                                                         \
    }                                                                        \
    { float t2_ = rs; pswap_f(t2_, rs); rs = t2_ + rs; }                     \
    lrun += rs;                                                              \
    _Pragma("unroll")                                                        \
    for (int st = 0; st < 2; st++) {                                         \
      union { u32 u[4]; bf16x8 v; } pf;                                      \
      u32 a0 = w8[4 * st], b0 = w8[4 * st + 2];                              \
      u32 a1 = w8[4 * st + 1], b1 = w8[4 * st + 3];                          \
      pswap_u(a0, b0);                                                       \
      pswap_u(a1, b1);                                                       \
      pf.u[0] = a0; pf.u[1] = a1; pf.u[2] = b0; pf.u[3] = b1;                \
      __builtin_amdgcn_s_setprio(1);                                         \
      o[0] = mfma32(st ? v2 : v0, pf.v, o[0]);                               \
      o[1] = mfma32(st ? v3 : v1, pf.v, o[1]);                               \
      __builtin_amdgcn_s_setprio(0);                                         \
    }                                                                        \
  } while (0)

  __syncthreads();  // lBH ready

  for (int t = 0; t < 64; t += 2) {
    // V(t) first, then K(t+1): PV's vmcnt wait on V leaves K in flight
    v0 = *(const bf16x8*)(vp);
    v1 = *(const bf16x8*)(vp + 256);
    v2 = *(const bf16x8*)(vp + 1024);
    v3 = *(const bf16x8*)(vp + 1280);
    kB0 = *(const bf16x8*)(kp);
    kB1 = *(const bf16x8*)(kp + 512);
    kB2 = *(const bf16x8*)(kp + 1024);
    kB3 = *(const bf16x8*)(kp + 1536);
    kp += 4096;
    vp += 4096;
    COMP(kA0, kA1, kA2, kA3, t);
    v0 = *(const bf16x8*)(vp);
    v1 = *(const bf16x8*)(vp + 256);
    v2 = *(const bf16x8*)(vp + 1024);
    v3 = *(const bf16x8*)(vp + 1280);
    kA0 = *(const bf16x8*)(kp);  // t=62: reads one tile past k_f (into v_f) — in-bounds of ws, unused
    kA1 = *(const bf16x8*)(kp + 512);
    kA2 = *(const bf16x8*)(kp + 1024);
    kA3 = *(const bf16x8*)(kp + 1536);
    kp += 4096;
    vp += 4096;
    COMP(kB0, kB1, kB2, kB3, t + 1);
  }
#undef COMP

  __syncthreads();  // all compute done before LDS reuse

  // ---- merge key halves: waves 2,3 publish; waves 0,1 combine + store ----
  float* MM = (float*)smem;          // m [2][32]
  float* ML = (float*)(smem + 256);  // l [2][32]
  float* MO = (float*)(smem + 512);  // O [2][32][64]
  if (w >= 2) {
    if (h == 0) { MM[qg * 32 + r5] = mrun; ML[qg * 32 + r5] = lrun; }
#pragma unroll
    for (int T = 0; T < 2; T++)
#pragma unroll
      for (int G = 0; G < 4; G++) {
        f32x4 ov;
#pragma unroll
        for (int i = 0; i < 4; i++) ov[i] = o[T][4 * G + i];
        *(f32x4*)&MO[qg * 2048 + r5 * 64 + T * 32 + G * 8 + h * 4] = ov;
      }
  }
  __syncthreads();
  if (w < 2) {
    const float mp = MM[qg * 32 + r5], lp = ML[qg * 32 + r5];
    const float mT = fmaxf(mrun, mp);
    const float a = __builtin_amdgcn_exp2f(mrun - mT);
    const float b = __builtin_amdgcn_exp2f(mp - mT);
    const float inv = 1.f / (lrun * a + lp * b);
#pragma unroll
    for (int T = 0; T < 2; T++)
#pragma unroll
      for (int G = 0; G < 4; G++) {
        f32x4 po = *(const f32x4*)&MO[qg * 2048 + r5 * 64 + T * 32 + G * 8 + h * 4];
        bf16x4 ob;
#pragma unroll
        for (int i = 0; i < 4; i++)
          ob[i] = (bf16)((o[T][4 * G + i] * a + po[i] * b) * inv);
        *(bf16x4*)&attn_out[sq * 768 + head * 64 + T * 32 + G * 8 + h * 4] = ob;
      }
  }
}

// ---------------- launch ----------------
extern "C" void kernel_launch(void* const* d_in, const int* in_sizes, int n_in,
                              void* d_out, int out_size, void* d_ws, size_t ws_size,
                              hipStream_t stream) {
  const float* x      = (const float*)d_in[0];
  const float* qkv_w  = (const float*)d_in[1];
  const float* qkv_b  = (const float*)d_in[2];
  const float* proj_w = (const float*)d_in[3];
  const float* proj_b = (const float*)d_in[4];
  const float* rph    = (const float*)d_in[5];
  const float* rpw    = (const float*)d_in[6];

  char* ws = (char*)d_ws;
  bf16*  xb    = (bf16*)(ws);                 //  6.29 MB [4096][768]
  bf16*  wqkv  = (bf16*)(ws + 6291456);       //  3.54 MB [2304][768]
  bf16*  wproj = (bf16*)(ws + 9830400);       //  1.18 MB [768][768]
  bf16*  q_s   = (bf16*)(ws + 11010048);      //  6.29 MB [12][4096][64]
  bf16*  k_f   = (bf16*)(ws + 17301504);      //  6.29 MB fragment-major K (scaled)
  bf16*  v_f   = (bf16*)(ws + 23592960);      //  6.29 MB fragment-major V
  bf16*  attno = (bf16*)(ws + 29884416);      //  6.29 MB [4096][768]
  float* bwv   = (float*)(ws + 36175872);     // 12.58 MB [12][4096][64]
  bf16*  rph_b = (bf16*)(ws + 48758784);      // 16 KB [127][64]
  bf16*  rpw_b = (bf16*)(ws + 48775040);      // 16 KB [127][64]

  cvt3<<<2696, 256, 0, stream>>>(x, xb, qkv_w, wqkv, proj_w, wproj,
                                 rph, rph_b, rpw, rpw_b);

  gemm128<0><<<dim3(18, 32), 256, 0, stream>>>(xb, wqkv, qkv_b, 768, 2304,
                                               q_s, k_f, v_f, nullptr);

  rel_pos_w<<<dim3(64, 12), 64, 0, stream>>>(q_s, rpw_b, bwv);

  flash_attn<<<768, 256, 0, stream>>>(q_s, k_f, v_f, rph_b, bwv, attno);

  gemm128<1><<<dim3(6, 32), 256, 0, stream>>>(attno, wproj, proj_b, 768, 768,
                                              nullptr, nullptr, nullptr,
                                              (float*)d_out);
}